// Round 1
// baseline (482.422 us; speedup 1.0000x reference)
//
#include <hip/hip_runtime.h>
#include <stdint.h>

#define S_LEN 2048
#define BATCH 8
#define EMB   1024
#define GAMMA 0.5f

typedef unsigned short ushort_t;
typedef __attribute__((ext_vector_type(8))) short  short8;
typedef __attribute__((ext_vector_type(8))) unsigned short ushort8;
typedef __attribute__((ext_vector_type(4))) float  floatx4;

__device__ __forceinline__ ushort_t f2bf(float f) {
  uint32_t x = __float_as_uint(f);
  x += 0x7fffu + ((x >> 16) & 1u);   // round-to-nearest-even
  return (ushort_t)(x >> 16);
}

__device__ __forceinline__ void gl_lds16(const ushort_t* g, ushort_t* l) {
  __builtin_amdgcn_global_load_lds(
      (const __attribute__((address_space(1))) unsigned int*)g,
      (__attribute__((address_space(3))) unsigned int*)l, 16, 0, 0);
}

// NT bf16 GEMM core: C(128x128) += A(128xK) * B(128xK)^T, both K-contiguous.
// 256 threads = 4 waves; wave quadrant 64x64; 16x16x32 MFMA, BK=32.
__device__ __forceinline__ void gemm_core(
    const ushort_t* __restrict__ A, const ushort_t* __restrict__ B,
    int lda, int ldb, int K,
    ushort_t* As, ushort_t* Bs, floatx4 (&acc)[4][4])
{
  const int tid  = threadIdx.x;
  const int wave = tid >> 6, lane = tid & 63;
  const int wr = (wave >> 1) * 64, wc = (wave & 1) * 64;
  const int lr = lane & 15, quad = lane >> 4;
  const int srow = lane >> 2;          // row within 16-row chunk
  const int scol = (lane & 3) * 8;     // bf16 col offset (16B units)
  const int c0 = wave * 2;

  for (int k0 = 0; k0 < K; k0 += 32) {
#pragma unroll
    for (int cc = 0; cc < 2; ++cc) {
      const int c = c0 + cc;
      gl_lds16(A + (size_t)(c * 16 + srow) * lda + k0 + scol, As + c * 512);
      gl_lds16(B + (size_t)(c * 16 + srow) * ldb + k0 + scol, Bs + c * 512);
    }
    __syncthreads();
    short8 af[4], bfr[4];
#pragma unroll
    for (int i = 0; i < 4; ++i)
      af[i] = *(const short8*)(As + (wr + i * 16 + lr) * 32 + quad * 8);
#pragma unroll
    for (int j = 0; j < 4; ++j)
      bfr[j] = *(const short8*)(Bs + (wc + j * 16 + lr) * 32 + quad * 8);
#pragma unroll
    for (int i = 0; i < 4; ++i) {
#pragma unroll
      for (int j = 0; j < 4; ++j)
        acc[i][j] = __builtin_amdgcn_mfma_f32_16x16x32_bf16(af[i], bfr[j], acc[i][j], 0, 0, 0);
    }
    __syncthreads();
  }
}

// ---------- quantize / pack ----------
__global__ __launch_bounds__(256) void k_quant_x(const float* __restrict__ X,
                                                 ushort_t* __restrict__ Xb) {
  size_t i = ((size_t)blockIdx.x * 256 + threadIdx.x) * 4;
  float4 v = *(const float4*)(X + i);
  *(ushort4*)(Xb + i) = make_ushort4(f2bf(v.x), f2bf(v.y), f2bf(v.z), f2bf(v.w));
}

__global__ __launch_bounds__(256) void k_quant_w(
    const float* __restrict__ Wq, const float* __restrict__ Wk,
    const float* __restrict__ Wv, ushort_t* __restrict__ W) {
  size_t i = ((size_t)blockIdx.x * 256 + threadIdx.x) * 4;
  int row = (int)(i >> 10), col = (int)(i & 1023);
  int sel = row >> 10, sr = row & 1023;
  const float* src = sel == 0 ? Wq : (sel == 1 ? Wk : Wv);
  float4 v = *(const float4*)(src + (size_t)sr * 1024 + col);
  *(ushort4*)(W + i) = make_ushort4(f2bf(v.x), f2bf(v.y), f2bf(v.z), f2bf(v.w));
}

__global__ __launch_bounds__(256) void k_bias_zero(
    const float* __restrict__ bq, const float* __restrict__ bk,
    const float* __restrict__ bv, float* __restrict__ bias,
    float* __restrict__ q2, float* __restrict__ k2, float* __restrict__ rsum) {
  int i = blockIdx.x * 256 + threadIdx.x;
  if (i < 1024)       bias[i] = bq[i];
  else if (i < 2048)  bias[i] = bk[i - 1024];
  else if (i < 3072)  bias[i] = bv[i - 2048];
  if (i < BATCH * S_LEN) { q2[i] = 0.f; k2[i] = 0.f; rsum[i] = 0.f; }
}

// ---------- GEMM 1: QKV projection ----------
// C[r,n] = X[r,:] . W[n,:] + bias[n];  r=(t,b) row-major; writes Q/K/V[b][t][e] bf16
// and q2/k2 row sums of squares (fp32).
__global__ __launch_bounds__(256) void k_gemm_qkv(
    const ushort_t* __restrict__ Xb, const ushort_t* __restrict__ W,
    const float* __restrict__ bias,
    ushort_t* __restrict__ Q, ushort_t* __restrict__ Kp, ushort_t* __restrict__ V,
    float* __restrict__ q2, float* __restrict__ k2) {
  __shared__ ushort_t As[4096], Bs[4096];
  const int mt = blockIdx.x * 128, nt = blockIdx.y * 128;
  floatx4 acc[4][4];
  const floatx4 z = {0.f, 0.f, 0.f, 0.f};
#pragma unroll
  for (int i = 0; i < 4; ++i)
#pragma unroll
    for (int j = 0; j < 4; ++j) acc[i][j] = z;

  gemm_core(Xb + (size_t)mt * EMB, W + (size_t)nt * EMB, EMB, EMB, EMB, As, Bs, acc);

  const int lane = threadIdx.x & 63, wave = threadIdx.x >> 6;
  const int wr = (wave >> 1) * 64, wc = (wave & 1) * 64;
  const int lr = lane & 15, quad = lane >> 4;
  const int which = nt >> 10;        // 0=q 1=k 2=v
  const int nc0 = nt & 1023;
  ushort_t* dst = which == 0 ? Q : (which == 1 ? Kp : V);
  float* sq = which == 0 ? q2 : k2;
  float bv4[4];
#pragma unroll
  for (int j = 0; j < 4; ++j) bv4[j] = bias[nt + wc + j * 16 + lr];

#pragma unroll
  for (int i = 0; i < 4; ++i) {
#pragma unroll
    for (int r = 0; r < 4; ++r) {
      const int g = mt + wr + i * 16 + quad * 4 + r;
      const int t = g >> 3, b = g & 7;
      float ss = 0.f;
#pragma unroll
      for (int j = 0; j < 4; ++j) {
        const float val = acc[i][j][r] + bv4[j];
        dst[(size_t)(b * S_LEN + t) * EMB + nc0 + wc + j * 16 + lr] = f2bf(val);
        ss += val * val;
      }
      if (which < 2) {
        ss += __shfl_xor(ss, 1);
        ss += __shfl_xor(ss, 2);
        ss += __shfl_xor(ss, 4);
        ss += __shfl_xor(ss, 8);
        if (lr == 0) atomicAdd(&sq[b * S_LEN + t], ss);
      }
    }
  }
}

// ---------- transpose V[b][j][e] -> Vt[b][e][j] ----------
__global__ __launch_bounds__(256) void k_transpose(const ushort_t* __restrict__ V,
                                                   ushort_t* __restrict__ Vt) {
  __shared__ ushort_t tile[64][72];
  const int b = blockIdx.z, j0 = blockIdx.x * 64, e0 = blockIdx.y * 64;
  const ushort_t* src = V + ((size_t)b * S_LEN + j0) * EMB + e0;
  const int tid = threadIdx.x;
#pragma unroll
  for (int rep = 0; rep < 2; ++rep) {
    const int lin = rep * 256 + tid;
    const int j = lin >> 3, e8 = (lin & 7) * 8;
    *(uint4*)&tile[j][e8] = *(const uint4*)(src + (size_t)j * EMB + e8);
  }
  __syncthreads();
  ushort_t* dst = Vt + ((size_t)b * EMB + e0) * S_LEN + j0;
#pragma unroll
  for (int rep = 0; rep < 2; ++rep) {
    const int lin = rep * 256 + tid;
    const int e = lin >> 3, j8 = (lin & 7) * 8;
    ushort8 o;
#pragma unroll
    for (int m = 0; m < 8; ++m) o[m] = tile[j8 + m][e];
    *(ushort8*)(dst + (size_t)e * S_LEN + j8) = o;
  }
}

// ---------- GEMM 2: logits + exp ----------
// P[t,j] = exp(-g*max(q2[t]+k2[j]-2*Q.K, 0)), bf16; rsum[t] += row partials.
__global__ __launch_bounds__(256) void k_logits(
    const ushort_t* __restrict__ Q, const ushort_t* __restrict__ Kp,
    const float* __restrict__ q2, const float* __restrict__ k2,
    ushort_t* __restrict__ P, float* __restrict__ rsum) {
  __shared__ ushort_t As[4096], Bs[4096];
  const int b = blockIdx.z;
  const int mt = blockIdx.x * 128, nt = blockIdx.y * 128;
  floatx4 acc[4][4];
  const floatx4 z = {0.f, 0.f, 0.f, 0.f};
#pragma unroll
  for (int i = 0; i < 4; ++i)
#pragma unroll
    for (int j = 0; j < 4; ++j) acc[i][j] = z;

  gemm_core(Q + ((size_t)b * S_LEN + mt) * EMB,
            Kp + ((size_t)b * S_LEN + nt) * EMB, EMB, EMB, EMB, As, Bs, acc);

  const int lane = threadIdx.x & 63, wave = threadIdx.x >> 6;
  const int wr = (wave >> 1) * 64, wc = (wave & 1) * 64;
  const int lr = lane & 15, quad = lane >> 4;
  float k2v[4];
#pragma unroll
  for (int j = 0; j < 4; ++j) k2v[j] = k2[b * S_LEN + nt + wc + j * 16 + lr];

#pragma unroll
  for (int i = 0; i < 4; ++i) {
#pragma unroll
    for (int r = 0; r < 4; ++r) {
      const int t = mt + wr + i * 16 + quad * 4 + r;
      const float q2v = q2[b * S_LEN + t];
      float ss = 0.f;
#pragma unroll
      for (int j = 0; j < 4; ++j) {
        float d2 = q2v + k2v[j] - 2.f * acc[i][j][r];
        d2 = fmaxf(d2, 0.f);
        const float p = __expf(-GAMMA * d2);
        P[((size_t)b * S_LEN + t) * S_LEN + nt + wc + j * 16 + lr] = f2bf(p);
        ss += p;
      }
      ss += __shfl_xor(ss, 1);
      ss += __shfl_xor(ss, 2);
      ss += __shfl_xor(ss, 4);
      ss += __shfl_xor(ss, 8);
      if (lr == 0) atomicAdd(&rsum[b * S_LEN + t], ss);
    }
  }
}

// ---------- GEMM 3: O = (P @ V) / rowsum ----------
__global__ __launch_bounds__(256) void k_out(
    const ushort_t* __restrict__ P, const ushort_t* __restrict__ Vt,
    const float* __restrict__ rsum, float* __restrict__ out) {
  __shared__ ushort_t As[4096], Bs[4096];
  const int b = blockIdx.z;
  const int mt = blockIdx.x * 128, nt = blockIdx.y * 128;
  floatx4 acc[4][4];
  const floatx4 z = {0.f, 0.f, 0.f, 0.f};
#pragma unroll
  for (int i = 0; i < 4; ++i)
#pragma unroll
    for (int j = 0; j < 4; ++j) acc[i][j] = z;

  gemm_core(P + ((size_t)b * S_LEN + mt) * S_LEN,
            Vt + ((size_t)b * EMB + nt) * S_LEN, S_LEN, S_LEN, S_LEN, As, Bs, acc);

  const int lane = threadIdx.x & 63, wave = threadIdx.x >> 6;
  const int wr = (wave >> 1) * 64, wc = (wave & 1) * 64;
  const int lr = lane & 15, quad = lane >> 4;
#pragma unroll
  for (int i = 0; i < 4; ++i) {
#pragma unroll
    for (int r = 0; r < 4; ++r) {
      const int t = mt + wr + i * 16 + quad * 4 + r;
      const float rinv = 1.f / rsum[b * S_LEN + t];
#pragma unroll
      for (int j = 0; j < 4; ++j) {
        const int e = nt + wc + j * 16 + lr;
        out[((size_t)t * BATCH + b) * EMB + e] = acc[i][j][r] * rinv;
      }
    }
  }
}

extern "C" void kernel_launch(void* const* d_in, const int* in_sizes, int n_in,
                              void* d_out, int out_size, void* d_ws, size_t ws_size,
                              hipStream_t stream) {
  (void)in_sizes; (void)n_in; (void)out_size; (void)ws_size;
  const float* X  = (const float*)d_in[0];
  const float* Wq = (const float*)d_in[1];
  const float* bq = (const float*)d_in[2];
  const float* Wk = (const float*)d_in[3];
  const float* bk = (const float*)d_in[4];
  const float* Wv = (const float*)d_in[5];
  const float* bv = (const float*)d_in[6];
  float* out = (float*)d_out;
  char* ws = (char*)d_ws;

  // workspace layout (bytes); Xb aliases P (Xb dead before P is written)
  ushort_t* Q    = (ushort_t*)(ws + 0);           //  33,554,432
  ushort_t* Kp   = (ushort_t*)(ws + 33554432);    //  33,554,432
  ushort_t* V    = (ushort_t*)(ws + 67108864);    //  33,554,432
  ushort_t* Vt   = (ushort_t*)(ws + 100663296);   //  33,554,432
  ushort_t* P    = (ushort_t*)(ws + 134217728);   //  67,108,864
  ushort_t* Xb   = (ushort_t*)(ws + 134217728);   //  alias of P[0:33.5M]
  ushort_t* Wqkv = (ushort_t*)(ws + 201326592);   //   6,291,456
  float*    bias = (float*)(ws + 207618048);      //      12,288
  float*    q2   = (float*)(ws + 207630336);      //      65,536
  float*    k2   = (float*)(ws + 207695872);      //      65,536
  float*    rsum = (float*)(ws + 207761408);      //      65,536  -> total ~198 MiB

  k_quant_x <<<16384, 256, 0, stream>>>(X, Xb);
  k_quant_w <<<3072, 256, 0, stream>>>(Wq, Wk, Wv, Wqkv);
  k_bias_zero<<<64, 256, 0, stream>>>(bq, bk, bv, bias, q2, k2, rsum);
  k_gemm_qkv<<<dim3(128, 24), 256, 0, stream>>>(Xb, Wqkv, bias, Q, Kp, V, q2, k2);
  k_transpose<<<dim3(32, 16, 8), 256, 0, stream>>>(V, Vt);
  k_logits  <<<dim3(16, 16, 8), 256, 0, stream>>>(Q, Kp, q2, k2, P, rsum);
  k_out     <<<dim3(16, 8, 8), 256, 0, stream>>>(P, Vt, rsum, out);
}